// Round 1
// baseline (1224.290 us; speedup 1.0000x reference)
//
#include <hip/hip_runtime.h>
#include <cstdint>

#define T_TOKENS 8192
#define DMODEL 1024
#define DFF 4096
#define NEXP 8

typedef _Float16 f16x8 __attribute__((ext_vector_type(8)));
typedef float f32x4 __attribute__((ext_vector_type(4)));
using u16 = unsigned short;

__device__ __forceinline__ u16 f2h(float f) {
  union { _Float16 h; u16 u; } v; v.h = (_Float16)f; return v.u;
}

// async global->LDS, 16B per lane. LDS dest is wave-uniform base + lane*16.
__device__ __forceinline__ void async16(const void* g, void* l) {
  __builtin_amdgcn_global_load_lds(
      (const __attribute__((address_space(1))) unsigned int*)(uintptr_t)g,
      (__attribute__((address_space(3))) unsigned int*)(uint32_t)(uintptr_t)l,
      16, 0, 0);
}

// ---------------- gating: fp64-exact logits, top-2, scatter to expert lists --
__global__ __launch_bounds__(256) void gate_kernel(
    const float* __restrict__ x, const float* __restrict__ gumbel,
    const float* __restrict__ gate_w, const float* __restrict__ gate_b,
    int* __restrict__ counts, int* __restrict__ tok_list, float* __restrict__ wt_list)
{
  int t = blockIdx.x * 4 + (threadIdx.x >> 6);
  int lane = threadIdx.x & 63;
  const float* xr = x + (size_t)t * DMODEL;
  double acc[NEXP];
#pragma unroll
  for (int e = 0; e < NEXP; ++e) acc[e] = 0.0;
#pragma unroll
  for (int i = 0; i < DMODEL / 64; ++i) {
    int d = lane + i * 64;
    float xv = xr[d];
    const float4* gw = (const float4*)(gate_w + (size_t)d * NEXP);
    float4 g0 = gw[0], g1 = gw[1];
    acc[0] += (double)xv * (double)g0.x;
    acc[1] += (double)xv * (double)g0.y;
    acc[2] += (double)xv * (double)g0.z;
    acc[3] += (double)xv * (double)g0.w;
    acc[4] += (double)xv * (double)g1.x;
    acc[5] += (double)xv * (double)g1.y;
    acc[6] += (double)xv * (double)g1.z;
    acc[7] += (double)xv * (double)g1.w;
  }
#pragma unroll
  for (int e = 0; e < NEXP; ++e) {
    double v = acc[e];
    for (int off = 32; off > 0; off >>= 1) v += __shfl_down(v, off, 64);
    acc[e] = v;
  }
  if (lane == 0) {
    float noisy[NEXP];
#pragma unroll
    for (int e = 0; e < NEXP; ++e)
      noisy[e] = (float)(acc[e] + (double)gate_b[e]) + gumbel[(size_t)t * NEXP + e];
    int i0 = 0;
    for (int e = 1; e < NEXP; ++e) if (noisy[e] > noisy[i0]) i0 = e;
    int i1 = -1;
    for (int e = 0; e < NEXP; ++e) {
      if (e == i0) continue;
      if (i1 < 0 || noisy[e] > noisy[i1]) i1 = e;
    }
    float ex = expf(noisy[i1] - noisy[i0]);
    float w0 = 1.0f / (1.0f + ex);
    float w1 = ex / (1.0f + ex);
    int p0 = atomicAdd(&counts[i0], 1);
    tok_list[i0 * T_TOKENS + p0] = t; wt_list[i0 * T_TOKENS + p0] = w0;
    int p1 = atomicAdd(&counts[i1], 1);
    tok_list[i1 * T_TOKENS + p1] = t; wt_list[i1 * T_TOKENS + p1] = w1;
  }
}

__global__ void offsets_kernel(const int* __restrict__ counts, int* __restrict__ offs) {
  if (threadIdx.x == 0 && blockIdx.x == 0) {
    int s = 0;
    for (int e = 0; e < NEXP; ++e) { offs[e] = s; s += counts[e]; }
  }
}

// ---------------- fp32 -> fp16 conversions -----------------------------------
__global__ __launch_bounds__(256) void cvt_f16_kernel(
    const float* __restrict__ in, u16* __restrict__ out, int n4)
{
  int i = blockIdx.x * 256 + threadIdx.x;
  if (i < n4) {
    float4 v = ((const float4*)in)[i];
    uint2 o;
    o.x = (unsigned)f2h(v.x) | ((unsigned)f2h(v.y) << 16);
    o.y = (unsigned)f2h(v.z) | ((unsigned)f2h(v.w) << 16);
    ((uint2*)out)[i] = o;
  }
}

// in [rows][cols] fp32 -> out [cols][rows] fp16, per-expert (blockIdx.z)
__global__ __launch_bounds__(256) void transpose_cvt_kernel(
    const float* __restrict__ in, u16* __restrict__ out, int rows, int cols)
{
  in  += (size_t)blockIdx.z * rows * cols;
  out += (size_t)blockIdx.z * rows * cols;
  int c0 = blockIdx.x * 64, r0 = blockIdx.y * 64;
  __shared__ u16 T[64][80];   // pad: row stride 160B, 16B-aligned
  int tid = threadIdx.x;
  int tr = tid >> 4;
  int tc = (tid & 15) * 4;
#pragma unroll
  for (int i = 0; i < 4; ++i) {
    int r = tr + i * 16;
    float4 v = *(const float4*)&in[(size_t)(r0 + r) * cols + (c0 + tc)];
    T[tc + 0][r] = f2h(v.x); T[tc + 1][r] = f2h(v.y);
    T[tc + 2][r] = f2h(v.z); T[tc + 3][r] = f2h(v.w);
  }
  __syncthreads();
  int orr = tid >> 3;
  int occ = (tid & 7) * 8;
#pragma unroll
  for (int i = 0; i < 2; ++i) {
    int r = orr + i * 32;
    uint4 d = *(const uint4*)&T[r][occ];
    *(uint4*)&out[(size_t)(c0 + r) * rows + (r0 + occ)] = d;
  }
}

// ---------------- GEMM1: H = relu(X[gather] @ W1 + b1), fp16 out -------------
// A: xh [8192][1024] fp16 (gathered rows). B: w1t [E][4096][1024] (k-major).
__global__ __launch_bounds__(256) void gemm1_kernel(
    const u16* __restrict__ xh, const u16* __restrict__ w1t,
    const float* __restrict__ b1,
    const int* __restrict__ counts, const int* __restrict__ offs,
    const int* __restrict__ tok_list, u16* __restrict__ H)
{
  const int e = blockIdx.z;
  const int count = counts[e];
  const int bm = blockIdx.x;
  if (bm * 128 >= count) return;
  const int bn = blockIdx.y;
  const int off = offs[e];

  __shared__ __align__(16) u16 As[128 * 32];
  __shared__ __align__(16) u16 Bs[128 * 32];

  const int tid = threadIdx.x;
  const int wid = tid >> 6, lane = tid & 63;
  const int wm = wid >> 1, wn = wid & 1;

  const int r0 = wid * 32 + (lane >> 2);
  const int kc = (lane & 3) * 8;
  int am0 = bm * 128 + r0;
  int am1 = am0 + 16;
  int cm1 = count - 1;
  int t0 = tok_list[e * T_TOKENS + (am0 < cm1 ? am0 : cm1)];
  int t1 = tok_list[e * T_TOKENS + (am1 < cm1 ? am1 : cm1)];
  const u16* ag0 = xh + (size_t)t0 * DMODEL + kc;
  const u16* ag1 = xh + (size_t)t1 * DMODEL + kc;
  const u16* bg0 = w1t + ((size_t)e * DFF + bn * 128 + r0) * DMODEL + kc;
  const u16* bg1 = bg0 + (size_t)16 * DMODEL;
  u16* asd0 = &As[(wid * 32) * 32];
  u16* asd1 = &As[(wid * 32 + 16) * 32];
  u16* bsd0 = &Bs[(wid * 32) * 32];
  u16* bsd1 = &Bs[(wid * 32 + 16) * 32];

  f32x4 acc[4][4] = {};

  for (int k0 = 0; k0 < DMODEL; k0 += 32) {
    async16(ag0 + k0, asd0);
    async16(ag1 + k0, asd1);
    async16(bg0 + k0, bsd0);
    async16(bg1 + k0, bsd1);
    __syncthreads();
    f16x8 af[4], bf[4];
#pragma unroll
    for (int f = 0; f < 4; ++f) {
      af[f] = *(const f16x8*)&As[(wm * 64 + f * 16 + (lane & 15)) * 32 + (lane >> 4) * 8];
      bf[f] = *(const f16x8*)&Bs[(wn * 64 + f * 16 + (lane & 15)) * 32 + (lane >> 4) * 8];
    }
#pragma unroll
    for (int fm = 0; fm < 4; ++fm)
#pragma unroll
      for (int fn = 0; fn < 4; ++fn)
        acc[fm][fn] = __builtin_amdgcn_mfma_f32_16x16x32_f16(af[fm], bf[fn], acc[fm][fn], 0, 0, 0);
    __syncthreads();
  }

  float b1v[4];
  const float* b1e = b1 + (size_t)e * DFF + bn * 128 + wn * 64 + (lane & 15);
#pragma unroll
  for (int fn = 0; fn < 4; ++fn) b1v[fn] = b1e[fn * 16];
#pragma unroll
  for (int fm = 0; fm < 4; ++fm)
#pragma unroll
    for (int i = 0; i < 4; ++i) {
      int row = wm * 64 + fm * 16 + (lane >> 4) * 4 + i;
      int m = bm * 128 + row;
      if (m < count) {
        u16* hr = H + (size_t)(off + m) * DFF + bn * 128 + wn * 64 + (lane & 15);
#pragma unroll
        for (int fn = 0; fn < 4; ++fn) {
          float v = acc[fm][fn][i] + b1v[fn];
          v = v > 0.f ? v : 0.f;
          hr[fn * 16] = f2h(v);
        }
      }
    }
}

// ---------------- GEMM2: out[tok] += wt * (H @ W2 + b2), atomic fp32 ---------
__global__ __launch_bounds__(256) void gemm2_kernel(
    const u16* __restrict__ H, const u16* __restrict__ w2t,
    const float* __restrict__ b2,
    const int* __restrict__ counts, const int* __restrict__ offs,
    const int* __restrict__ tok_list, const float* __restrict__ wt_list,
    float* __restrict__ out)
{
  const int e = blockIdx.z;
  const int count = counts[e];
  const int bm = blockIdx.x;
  if (bm * 128 >= count) return;
  const int bn = blockIdx.y;
  const int off = offs[e];

  __shared__ __align__(16) u16 As[128 * 32];
  __shared__ __align__(16) u16 Bs[128 * 32];
  __shared__ int tok_s[128];
  __shared__ float wt_s[128];

  const int tid = threadIdx.x;
  if (tid < 128) {
    int m = bm * 128 + tid;
    bool v = m < count;
    tok_s[tid] = v ? tok_list[e * T_TOKENS + m] : -1;
    wt_s[tid] = v ? wt_list[e * T_TOKENS + m] : 0.f;
  }

  const int wid = tid >> 6, lane = tid & 63;
  const int wm = wid >> 1, wn = wid & 1;
  const int r0 = wid * 32 + (lane >> 2);
  const int kc = (lane & 3) * 8;
  int am0 = bm * 128 + r0;
  int am1 = am0 + 16;
  int cm1 = count - 1;
  int h0 = off + (am0 < cm1 ? am0 : cm1);
  int h1 = off + (am1 < cm1 ? am1 : cm1);
  const u16* ag0 = H + (size_t)h0 * DFF + kc;
  const u16* ag1 = H + (size_t)h1 * DFF + kc;
  const u16* bg0 = w2t + ((size_t)e * DMODEL + bn * 128 + r0) * DFF + kc;
  const u16* bg1 = bg0 + (size_t)16 * DFF;
  u16* asd0 = &As[(wid * 32) * 32];
  u16* asd1 = &As[(wid * 32 + 16) * 32];
  u16* bsd0 = &Bs[(wid * 32) * 32];
  u16* bsd1 = &Bs[(wid * 32 + 16) * 32];

  f32x4 acc[4][4] = {};

  for (int k0 = 0; k0 < DFF; k0 += 32) {
    async16(ag0 + k0, asd0);
    async16(ag1 + k0, asd1);
    async16(bg0 + k0, bsd0);
    async16(bg1 + k0, bsd1);
    __syncthreads();
    f16x8 af[4], bf[4];
#pragma unroll
    for (int f = 0; f < 4; ++f) {
      af[f] = *(const f16x8*)&As[(wm * 64 + f * 16 + (lane & 15)) * 32 + (lane >> 4) * 8];
      bf[f] = *(const f16x8*)&Bs[(wn * 64 + f * 16 + (lane & 15)) * 32 + (lane >> 4) * 8];
    }
#pragma unroll
    for (int fm = 0; fm < 4; ++fm)
#pragma unroll
      for (int fn = 0; fn < 4; ++fn)
        acc[fm][fn] = __builtin_amdgcn_mfma_f32_16x16x32_f16(af[fm], bf[fn], acc[fm][fn], 0, 0, 0);
    __syncthreads();
  }

  float b2v[4];
  const float* b2e = b2 + (size_t)e * DMODEL + bn * 128 + wn * 64 + (lane & 15);
#pragma unroll
  for (int fn = 0; fn < 4; ++fn) b2v[fn] = b2e[fn * 16];
#pragma unroll
  for (int fm = 0; fm < 4; ++fm)
#pragma unroll
    for (int i = 0; i < 4; ++i) {
      int row = wm * 64 + fm * 16 + (lane >> 4) * 4 + i;
      int tok = tok_s[row];
      if (tok >= 0) {
        float w = wt_s[row];
        float* orow = out + (size_t)tok * DMODEL + bn * 128 + wn * 64 + (lane & 15);
#pragma unroll
        for (int fn = 0; fn < 4; ++fn)
          atomicAdd(&orow[fn * 16], w * (acc[fm][fn][i] + b2v[fn]));
      }
    }
}

// ---------------- launch -----------------------------------------------------
extern "C" void kernel_launch(void* const* d_in, const int* in_sizes, int n_in,
                              void* d_out, int out_size, void* d_ws, size_t ws_size,
                              hipStream_t stream)
{
  const float* x      = (const float*)d_in[0];
  const float* gumbel = (const float*)d_in[1];
  const float* gate_w = (const float*)d_in[2];
  const float* gate_b = (const float*)d_in[3];
  const float* w1     = (const float*)d_in[4];
  const float* b1     = (const float*)d_in[5];
  const float* w2     = (const float*)d_in[6];
  const float* b2     = (const float*)d_in[7];
  float* out = (float*)d_out;
  char* ws = (char*)d_ws;

  // workspace layout (needs ~273 MB)
  constexpr size_t OFF_COUNTS = 0;                                   // 8 ints
  constexpr size_t OFF_OFFS   = 64;                                  // 8 ints
  constexpr size_t OFF_TOK    = 1024;                                // 8*8192 int
  constexpr size_t OFF_WT     = OFF_TOK + (size_t)NEXP * T_TOKENS * 4;
  constexpr size_t OFF_XH     = 589824;
  constexpr size_t OFF_W1T    = OFF_XH  + (size_t)T_TOKENS * DMODEL * 2;
  constexpr size_t OFF_W2T    = OFF_W1T + (size_t)NEXP * DFF * DMODEL * 2;
  constexpr size_t OFF_H      = OFF_W2T + (size_t)NEXP * DMODEL * DFF * 2;

  int*   counts = (int*)(ws + OFF_COUNTS);
  int*   offs   = (int*)(ws + OFF_OFFS);
  int*   tokl   = (int*)(ws + OFF_TOK);
  float* wtl    = (float*)(ws + OFF_WT);
  u16*   xh     = (u16*)(ws + OFF_XH);
  u16*   w1t    = (u16*)(ws + OFF_W1T);
  u16*   w2t    = (u16*)(ws + OFF_W2T);
  u16*   H      = (u16*)(ws + OFF_H);

  hipMemsetAsync(ws + OFF_COUNTS, 0, 1024, stream);
  hipMemsetAsync(d_out, 0, (size_t)out_size * sizeof(float), stream);

  cvt_f16_kernel<<<(T_TOKENS * DMODEL / 4 + 255) / 256, 256, 0, stream>>>(
      x, xh, T_TOKENS * DMODEL / 4);
  transpose_cvt_kernel<<<dim3(DFF / 64, DMODEL / 64, NEXP), 256, 0, stream>>>(
      w1, w1t, DMODEL, DFF);
  transpose_cvt_kernel<<<dim3(DMODEL / 64, DFF / 64, NEXP), 256, 0, stream>>>(
      w2, w2t, DFF, DMODEL);
  gate_kernel<<<T_TOKENS / 4, 256, 0, stream>>>(
      x, gumbel, gate_w, gate_b, counts, tokl, wtl);
  offsets_kernel<<<1, 64, 0, stream>>>(counts, offs);
  gemm1_kernel<<<dim3(64, DFF / 128, NEXP), 256, 0, stream>>>(
      xh, w1t, b1, counts, offs, tokl, H);
  gemm2_kernel<<<dim3(64, DMODEL / 128, NEXP), 256, 0, stream>>>(
      H, w2t, b2, counts, offs, tokl, wtl, out);
}